// Round 6
// baseline (162.419 us; speedup 1.0000x reference)
//
#include <hip/hip_runtime.h>

#define NB    2048
#define AMAX  64
#define EDIM  128
#define TOTAL 66560          // = 520 * 128
#define DHEAD 16
#define LSTR  136            // LDS row stride in fp16 (128 + 8 pad)

typedef _Float16 f16x8 __attribute__((ext_vector_type(8)));
typedef _Float16 f16x4 __attribute__((ext_vector_type(4)));
typedef float    f32x4 __attribute__((ext_vector_type(4)));

// load 8 consecutive f32 and convert to f16x8 (RTNE, same as a prep-pass conversion)
static __device__ __forceinline__ f16x8 ldcvt8(const float* __restrict__ p) {
    const float4 a0 = *(const float4*)p;
    const float4 a1 = *(const float4*)(p + 4);
    f16x8 h;
    h[0]=(_Float16)a0.x; h[1]=(_Float16)a0.y; h[2]=(_Float16)a0.z; h[3]=(_Float16)a0.w;
    h[4]=(_Float16)a1.x; h[5]=(_Float16)a1.y; h[6]=(_Float16)a1.z; h[7]=(_Float16)a1.w;
    return h;
}

// ---------------- single fully fused kernel ----------------
// 1 sample per block (LPT heavy-first mapping), 4 waves; wave w owns heads {2w,2w+1},
// interleaved (r5-proven). New in r6: no prep kernel at all —
//  * per-block offset computed in-kernel: off = sum_{i<b} ag[i] (8 masked loads/thread
//    over the 8KB L1-resident ag + wave reduce + LDS exchange)
//  * weights read as f32 and converted to f16 in-register at fragment load; proj loop
//    is ks->m->kt so each of the 24 weight fragments is loaded+converted exactly once,
//    with aq/ak/av[m][kt] accumulators carried across ks.
// Everything downstream (attention body, ctx exchange, column-split out-projection)
// is the r5-proven structure, bit-identical math.
__global__ __launch_bounds__(256, 2) void fused_attn_kernel(
    const float* __restrict__ x,     // [TOTAL][128] f32
    const float* __restrict__ win,   // [384][128] f32
    const float* __restrict__ bin,   // [384] f32
    const float* __restrict__ wout,  // [128][128] f32
    const float* __restrict__ bout,  // [128] f32
    const int*   __restrict__ ag,    // [NB]
    float*       __restrict__ out)   // [TOTAL][128] f32
{
    __shared__ __align__(16) _Float16 xs[AMAX * LSTR];   // 17408 B; x tile, then ctx
    __shared__ int offp[4];

    const int i    = blockIdx.x;
    const int b    = (((63 - (i >> 5)) * 55) & 63) + ((i & 31) << 6);   // LPT: heavy first
    const int tid  = threadIdx.x;
    const int lane = tid & 63;
    const int wid  = __builtin_amdgcn_readfirstlane(tid >> 6);
    const int l15  = lane & 15;
    const int quad = lane >> 4;

    // ---- per-block exclusive-prefix offset: off = sum_{idx < b} ag[idx] ----
    int pacc = 0;
    {
        const int base8 = tid * 8;
#pragma unroll
        for (int j = 0; j < 8; ++j) {
            const int idx = base8 + j;
            const int v = ag[idx];
            pacc += (idx < b) ? v : 0;
        }
#pragma unroll
        for (int d = 1; d < 64; d <<= 1) pacc += __shfl_xor(pacc, d, 64);
        if (lane == 0) offp[wid] = pacc;
    }
    const int n  = ag[b];
    const int nt = (n + 15) >> 4;
    __syncthreads();
    const int off = offp[0] + offp[1] + offp[2] + offp[3];

    // ---- stage x -> xs (f16), zero-fill rows >= n ----
#pragma unroll
    for (int it = 0; it < 4; ++it) {
        const int u = it * 256 + tid;        // 1024 units of 8 halfs
        const int r = u >> 4, c8 = u & 15;
        f16x8 hv = {};
        if (r < n) {
            const float4 a0 = *(const float4*)(x + (size_t)(off + r) * EDIM + c8 * 8);
            const float4 a1 = *(const float4*)(x + (size_t)(off + r) * EDIM + c8 * 8 + 4);
            hv[0]=(_Float16)a0.x; hv[1]=(_Float16)a0.y; hv[2]=(_Float16)a0.z; hv[3]=(_Float16)a0.w;
            hv[4]=(_Float16)a1.x; hv[5]=(_Float16)a1.y; hv[6]=(_Float16)a1.z; hv[7]=(_Float16)a1.w;
        }
        *(f16x8*)(xs + r * LSTR + c8 * 8) = hv;
    }
    __syncthreads();

    // ---- biases (f32 direct) ----
    float bqa[2][4], bka[2][4], bva[2];
#pragma unroll
    for (int m = 0; m < 2; ++m) {
        const int h = wid * 2 + m;
        const float4 bq = *(const float4*)(bin + h * 16 + quad * 4);
        const float4 bk = *(const float4*)(bin + 128 + h * 16 + quad * 4);
        bqa[m][0]=bq.x; bqa[m][1]=bq.y; bqa[m][2]=bq.z; bqa[m][3]=bq.w;
        bka[m][0]=bk.x; bka[m][1]=bk.y; bka[m][2]=bk.z; bka[m][3]=bk.w;
        bva[m] = bin[256 + h * 16 + l15];
    }

    // ---- QKV projection: ks outer so each weight fragment is loaded+converted once ----
    f32x4 aq[2][4], ak[2][4], av[2][4];
#pragma unroll
    for (int m = 0; m < 2; ++m)
#pragma unroll
        for (int kt = 0; kt < 4; ++kt) {
            aq[m][kt] = (f32x4){0.f,0.f,0.f,0.f};
            ak[m][kt] = (f32x4){0.f,0.f,0.f,0.f};
            av[m][kt] = (f32x4){0.f,0.f,0.f,0.f};
        }
#pragma unroll
    for (int ks = 0; ks < 4; ++ks) {
        f16x8 xf[4];
#pragma unroll
        for (int kt = 0; kt < 4; ++kt) if (kt < nt)
            xf[kt] = *(const f16x8*)(xs + (kt * 16 + l15) * LSTR + ks * 32 + quad * 8);
#pragma unroll
        for (int m = 0; m < 2; ++m) {
            const int h = wid * 2 + m;
            const f16x8 wqf = ldcvt8(win + (size_t)(h * 16 + l15) * EDIM + ks * 32 + quad * 8);
            const f16x8 wkf = ldcvt8(win + (size_t)(128 + h * 16 + l15) * EDIM + ks * 32 + quad * 8);
            const f16x8 wvf = ldcvt8(win + (size_t)(256 + h * 16 + l15) * EDIM + ks * 32 + quad * 8);
#pragma unroll
            for (int kt = 0; kt < 4; ++kt) if (kt < nt) {
                aq[m][kt] = __builtin_amdgcn_mfma_f32_16x16x32_f16(wqf, xf[kt], aq[m][kt], 0, 0, 0);
                ak[m][kt] = __builtin_amdgcn_mfma_f32_16x16x32_f16(wkf, xf[kt], ak[m][kt], 0, 0, 0);
                av[m][kt] = __builtin_amdgcn_mfma_f32_16x16x32_f16(xf[kt], wvf, av[m][kt], 0, 0, 0);
            }
        }
    }
    f16x4 qf[2][4], kf[2][4], vf[2][4];
#pragma unroll
    for (int m = 0; m < 2; ++m)
#pragma unroll
        for (int kt = 0; kt < 4; ++kt) if (kt < nt) {
#pragma unroll
            for (int r = 0; r < 4; ++r) {
                qf[m][kt][r] = (_Float16)((aq[m][kt][r] + bqa[m][r]) * 0.25f);   // 1/sqrt(16)
                kf[m][kt][r] = (_Float16)(ak[m][kt][r] + bka[m][r]);
                vf[m][kt][r] = (_Float16)(av[m][kt][r] + bva[m]);
            }
        }

    // ---- attention: both heads interleaved; 2 shuffles per head per q-tile ----
    f16x4 ctxf[2][4] = {};   // [head m][qtile]; elem r -> q=qt*16+quad*4+r, d=l15
#pragma unroll
    for (int qt = 0; qt < 4; ++qt) if (qt < nt) {
        f32x4 sv0[4], sv1[4];
#pragma unroll
        for (int kt = 0; kt < 4; ++kt) if (kt < nt) {
            sv0[kt] = __builtin_amdgcn_mfma_f32_16x16x16f16(
                          kf[0][kt], qf[0][qt], (f32x4){0.f,0.f,0.f,0.f}, 0, 0, 0);
            sv1[kt] = __builtin_amdgcn_mfma_f32_16x16x16f16(
                          kf[1][kt], qf[1][qt], (f32x4){0.f,0.f,0.f,0.f}, 0, 0, 0);
        }
        // exp + per-kt partial sums (short dependence chains), then pairwise tree
        float t0[4], t1[4];
#pragma unroll
        for (int kt = 0; kt < 4; ++kt) { t0[kt] = 0.f; t1[kt] = 0.f; }
#pragma unroll
        for (int kt = 0; kt < 4; ++kt) if (kt < nt) {
            float s0 = 0.f, s1 = 0.f;
#pragma unroll
            for (int r = 0; r < 4; ++r) {
                const int key = kt * 16 + quad * 4 + r;
                const float p0 = (key < n) ? __expf(sv0[kt][r]) : 0.f;
                const float p1 = (key < n) ? __expf(sv1[kt][r]) : 0.f;
                s0 += p0; sv0[kt][r] = p0;
                s1 += p1; sv1[kt][r] = p1;
            }
            t0[kt] = s0; t1[kt] = s1;
        }
        float ls0 = (t0[0] + t0[1]) + (t0[2] + t0[3]);
        float ls1 = (t1[0] + t1[1]) + (t1[2] + t1[3]);
        ls0 += __shfl_xor(ls0, 16, 64);
        ls1 += __shfl_xor(ls1, 16, 64);
        ls0 += __shfl_xor(ls0, 32, 64);
        ls1 += __shfl_xor(ls1, 32, 64);
        const float inv0 = 1.0f / ls0;
        const float inv1 = 1.0f / ls1;
        f16x4 pf0[4], pf1[4];
#pragma unroll
        for (int kt = 0; kt < 4; ++kt) if (kt < nt) {
#pragma unroll
            for (int r = 0; r < 4; ++r) {
                pf0[kt][r] = (_Float16)(sv0[kt][r] * inv0);
                pf1[kt][r] = (_Float16)(sv1[kt][r] * inv1);
            }
        }
        // PV with split accumulators (even/odd kt), both heads independent
        f32x4 a0A = (f32x4){0.f,0.f,0.f,0.f}, a0B = (f32x4){0.f,0.f,0.f,0.f};
        f32x4 a1A = (f32x4){0.f,0.f,0.f,0.f}, a1B = (f32x4){0.f,0.f,0.f,0.f};
#pragma unroll
        for (int kt = 0; kt < 4; ++kt) if (kt < nt) {
            if ((kt & 1) == 0) {
                a0A = __builtin_amdgcn_mfma_f32_16x16x16f16(pf0[kt], vf[0][kt], a0A, 0, 0, 0);
                a1A = __builtin_amdgcn_mfma_f32_16x16x16f16(pf1[kt], vf[1][kt], a1A, 0, 0, 0);
            } else {
                a0B = __builtin_amdgcn_mfma_f32_16x16x16f16(pf0[kt], vf[0][kt], a0B, 0, 0, 0);
                a1B = __builtin_amdgcn_mfma_f32_16x16x16f16(pf1[kt], vf[1][kt], a1B, 0, 0, 0);
            }
        }
#pragma unroll
        for (int r = 0; r < 4; ++r) {
            ctxf[0][qt][r] = (_Float16)(a0A[r] + a0B[r]);
            ctxf[1][qt][r] = (_Float16)(a1A[r] + a1B[r]);
        }
    }

    // ---- ctx -> LDS (reuse xs; all xs reads are done before this barrier) ----
    __syncthreads();
#pragma unroll
    for (int m = 0; m < 2; ++m) {
        const int h = wid * 2 + m;
#pragma unroll
        for (int qt = 0; qt < 4; ++qt) if (qt < nt) {
#pragma unroll
            for (int r = 0; r < 4; ++r)
                xs[(qt * 16 + quad * 4 + r) * LSTR + h * 16 + l15] = ctxf[m][qt][r];
        }
    }
    __syncthreads();

    // ---- out-projection, column-split: wave w -> cols [32w,32w+32), all row tiles ----
    {
        f32x4 oacc[4][2];
#pragma unroll
        for (int t = 0; t < 4; ++t) { oacc[t][0] = (f32x4){0.f,0.f,0.f,0.f}; oacc[t][1] = (f32x4){0.f,0.f,0.f,0.f}; }
#pragma unroll
        for (int ks = 0; ks < 4; ++ks) {
            const f16x8 cf0 = ldcvt8(wout + (size_t)(wid * 32 + l15) * EDIM + ks * 32 + quad * 8);
            const f16x8 cf1 = ldcvt8(wout + (size_t)(wid * 32 + 16 + l15) * EDIM + ks * 32 + quad * 8);
#pragma unroll
            for (int t = 0; t < 4; ++t) if (t < nt) {
                const f16x8 rf = *(const f16x8*)(xs + (t * 16 + l15) * LSTR + ks * 32 + quad * 8);
                oacc[t][0] = __builtin_amdgcn_mfma_f32_16x16x32_f16(cf0, rf, oacc[t][0], 0, 0, 0);
                oacc[t][1] = __builtin_amdgcn_mfma_f32_16x16x32_f16(cf1, rf, oacc[t][1], 0, 0, 0);
            }
        }
        const float4 bo0 = *(const float4*)(bout + wid * 32 + quad * 4);
        const float4 bo1 = *(const float4*)(bout + wid * 32 + 16 + quad * 4);
#pragma unroll
        for (int t = 0; t < 4; ++t) if (t < nt) {
            const int row = t * 16 + l15;
            if (row < n) {
                float* orow = out + (size_t)(off + row) * EDIM + wid * 32;
                *(float4*)(orow + quad * 4) =
                    make_float4(oacc[t][0][0] + bo0.x, oacc[t][0][1] + bo0.y,
                                oacc[t][0][2] + bo0.z, oacc[t][0][3] + bo0.w);
                *(float4*)(orow + 16 + quad * 4) =
                    make_float4(oacc[t][1][0] + bo1.x, oacc[t][1][1] + bo1.y,
                                oacc[t][1][2] + bo1.z, oacc[t][1][3] + bo1.w);
            }
        }
    }
}

extern "C" void kernel_launch(void* const* d_in, const int* in_sizes, int n_in,
                              void* d_out, int out_size, void* d_ws, size_t ws_size,
                              hipStream_t stream) {
    const float* x   = (const float*)d_in[0];
    const float* win = (const float*)d_in[1];
    const float* bin = (const float*)d_in[2];
    const float* wo  = (const float*)d_in[3];
    const float* bo  = (const float*)d_in[4];
    const int*   ag  = (const int*)d_in[5];
    float* out = (float*)d_out;
    (void)d_ws; (void)ws_size;

    fused_attn_kernel<<<NB, 256, 0, stream>>>(x, win, bin, wo, bo, ag, out);
}

// Round 9
// 138.194 us; speedup vs baseline: 1.1753x; 1.1753x over previous
//
#include <hip/hip_runtime.h>

#define NB    2048
#define AMAX  64
#define EDIM  128
#define TOTAL 66560          // = 520 * 128
#define DHEAD 16
#define KVSTR 20
#define XSTR  129
#define LSTR  136            // LDS row stride in fp16 (128 + 8 pad)
#define WELEM 65536          // winh (49152) + woh (16384) halfs

typedef _Float16 f16x8 __attribute__((ext_vector_type(8)));
typedef _Float16 f16x4 __attribute__((ext_vector_type(4)));
typedef float    f32x4 __attribute__((ext_vector_type(4)));

// ---------------- prep: block 0 = exclusive scan of agents; blocks 1..64 convert
// win (49152 f32) and wout (16384 f32) into contiguous f16 wh[] ----------------
__global__ __launch_bounds__(256) void prep_kernel(const int* __restrict__ ag,
                                                   int* __restrict__ offs,
                                                   const float* __restrict__ win,
                                                   const float* __restrict__ wout,
                                                   _Float16* __restrict__ wh) {
    if (blockIdx.x == 0) {
        __shared__ int part[256];
        const int t = threadIdx.x;
        int loc[8];
        int s = 0;
#pragma unroll
        for (int i = 0; i < 8; ++i) { loc[i] = s; s += ag[t * 8 + i]; }
        part[t] = s;
        __syncthreads();
        for (int d = 1; d < 256; d <<= 1) {
            int v = (t >= d) ? part[t - d] : 0;
            __syncthreads();
            part[t] += v;
            __syncthreads();
        }
        const int base = (t == 0) ? 0 : part[t - 1];
#pragma unroll
        for (int i = 0; i < 8; ++i) offs[t * 8 + i] = base + loc[i];
    } else {
        // blocks 1..48 -> win, 49..64 -> wout (1024-elem chunks never straddle)
        const int base = (blockIdx.x - 1) * 1024 + threadIdx.x * 4;
        const float4 v = (base < 49152) ? *(const float4*)(win + base)
                                        : *(const float4*)(wout + (base - 49152));
        f16x4 h;
        h[0] = (_Float16)v.x; h[1] = (_Float16)v.y;
        h[2] = (_Float16)v.z; h[3] = (_Float16)v.w;
        *(f16x4*)(wh + base) = h;
    }
}

// ---------------- fully fused: QKV projection + flash attention + out-projection ----------------
// r5-proven structure: 1 sample/block (LPT heavy-first), 4 waves, wave w owns heads
// {2w,2w+1} INTERLEAVED; f16 weights from workspace; LDS x-stage reused for ctx;
// column-split out-projection. r7 chain cuts:
//  * weight/bias loads hoisted ABOVE the staging loop (global latency overlaps stage+barrier)
//  * staging skips whole 16-row tiles >= nt (wave-uniform guard)
//  * softmax via native exp2: q pre-scaled by 0.25*log2(e), p = v_exp_f32(s)
//  * denominator reciprocal via v_rcp_f32 (1 ulp, << 1e-3 tolerance)
__global__ __launch_bounds__(256, 2) void fused_attn_kernel(
    const float*    __restrict__ x,     // [TOTAL][128] f32
    const _Float16* __restrict__ winh,  // [384][128] f16
    const float*    __restrict__ bin,   // [384] f32
    const _Float16* __restrict__ woh,   // [128][128] f16
    const float*    __restrict__ bout,  // [128] f32
    const int*      __restrict__ ag,
    const int*      __restrict__ offs,
    float*          __restrict__ out)   // [TOTAL][128] f32
{
    __shared__ __align__(16) _Float16 xs[AMAX * LSTR];   // 17408 B; x tile, then ctx

    const int i    = blockIdx.x;
    const int b    = (((63 - (i >> 5)) * 55) & 63) + ((i & 31) << 6);   // LPT: heavy first
    const int n    = ag[b];
    const int off  = offs[b];
    const int tid  = threadIdx.x;
    const int lane = tid & 63;
    const int wid  = __builtin_amdgcn_readfirstlane(tid >> 6);
    const int l15  = lane & 15;
    const int quad = lane >> 4;
    const int nt   = (n + 15) >> 4;

    // ---- weight fragments + biases FIRST: latency overlaps the x stage below ----
    f16x8 wq[2][4], wk[2][4], wv[2][4];
    float bqa[2][4], bka[2][4], bva[2];
#pragma unroll
    for (int m = 0; m < 2; ++m) {
        const int h = wid * 2 + m;
#pragma unroll
        for (int ks = 0; ks < 4; ++ks) {
            wq[m][ks] = *(const f16x8*)(winh + (size_t)(h * 16 + l15) * EDIM + ks * 32 + quad * 8);
            wk[m][ks] = *(const f16x8*)(winh + (size_t)(128 + h * 16 + l15) * EDIM + ks * 32 + quad * 8);
            wv[m][ks] = *(const f16x8*)(winh + (size_t)(256 + h * 16 + l15) * EDIM + ks * 32 + quad * 8);
        }
        const float4 bq = *(const float4*)(bin + h * 16 + quad * 4);
        const float4 bk = *(const float4*)(bin + 128 + h * 16 + quad * 4);
        bqa[m][0]=bq.x; bqa[m][1]=bq.y; bqa[m][2]=bq.z; bqa[m][3]=bq.w;
        bka[m][0]=bk.x; bka[m][1]=bk.y; bka[m][2]=bk.z; bka[m][3]=bk.w;
        bva[m] = bin[256 + h * 16 + l15];
    }

    // ---- stage x -> xs (f16); only tiles < nt are ever read downstream ----
#pragma unroll
    for (int it = 0; it < 4; ++it) if (it < nt) {
        const int u = it * 256 + tid;        // tile it rows [16it,16it+16)
        const int r = u >> 4, c8 = u & 15;
        f16x8 hv = {};
        if (r < n) {
            const float4 a0 = *(const float4*)(x + (size_t)(off + r) * EDIM + c8 * 8);
            const float4 a1 = *(const float4*)(x + (size_t)(off + r) * EDIM + c8 * 8 + 4);
            hv[0]=(_Float16)a0.x; hv[1]=(_Float16)a0.y; hv[2]=(_Float16)a0.z; hv[3]=(_Float16)a0.w;
            hv[4]=(_Float16)a1.x; hv[5]=(_Float16)a1.y; hv[6]=(_Float16)a1.z; hv[7]=(_Float16)a1.w;
        }
        *(f16x8*)(xs + r * LSTR + c8 * 8) = hv;
    }
    __syncthreads();

    // ---- QKV projection: each xf read once, 6 independent MFMA chains ----
    // q pre-scaled by 0.25*log2(e) so softmax can use native exp2 directly.
    const float QSC = 0.25f * 1.44269504088896f;
    f16x4 qf[2][4], kf[2][4], vf[2][4];
#pragma unroll
    for (int kt = 0; kt < 4; ++kt) if (kt < nt) {
        f16x8 xf[4];
#pragma unroll
        for (int ks = 0; ks < 4; ++ks)
            xf[ks] = *(const f16x8*)(xs + (kt * 16 + l15) * LSTR + ks * 32 + quad * 8);
#pragma unroll
        for (int m = 0; m < 2; ++m) {
            f32x4 aq = (f32x4){0.f,0.f,0.f,0.f};
            f32x4 ak = (f32x4){0.f,0.f,0.f,0.f};
            f32x4 av = (f32x4){0.f,0.f,0.f,0.f};
#pragma unroll
            for (int ks = 0; ks < 4; ++ks) {
                aq = __builtin_amdgcn_mfma_f32_16x16x32_f16(wq[m][ks], xf[ks], aq, 0, 0, 0);
                ak = __builtin_amdgcn_mfma_f32_16x16x32_f16(wk[m][ks], xf[ks], ak, 0, 0, 0);
                av = __builtin_amdgcn_mfma_f32_16x16x32_f16(xf[ks], wv[m][ks], av, 0, 0, 0);
            }
#pragma unroll
            for (int r = 0; r < 4; ++r) {
                qf[m][kt][r] = (_Float16)((aq[r] + bqa[m][r]) * QSC);
                kf[m][kt][r] = (_Float16)(ak[r] + bka[m][r]);
                vf[m][kt][r] = (_Float16)(av[r] + bva[m]);
            }
        }
    }

    // ---- attention: both heads interleaved; 2 shuffles per head per q-tile ----
    f16x4 ctxf[2][4] = {};   // [head m][qtile]; elem r -> q=qt*16+quad*4+r, d=l15
#pragma unroll
    for (int qt = 0; qt < 4; ++qt) if (qt < nt) {
        f32x4 sv0[4], sv1[4];
#pragma unroll
        for (int kt = 0; kt < 4; ++kt) if (kt < nt) {
            sv0[kt] = __builtin_amdgcn_mfma_f32_16x16x16f16(
                          kf[0][kt], qf[0][qt], (f32x4){0.f,0.f,0.f,0.f}, 0, 0, 0);
            sv1[kt] = __builtin_amdgcn_mfma_f32_16x16x16f16(
                          kf[1][kt], qf[1][qt], (f32x4){0.f,0.f,0.f,0.f}, 0, 0, 0);
        }
        float t0[4], t1[4];
#pragma unroll
        for (int kt = 0; kt < 4; ++kt) { t0[kt] = 0.f; t1[kt] = 0.f; }
#pragma unroll
        for (int kt = 0; kt < 4; ++kt) if (kt < nt) {
            float s0 = 0.f, s1 = 0.f;
#pragma unroll
            for (int r = 0; r < 4; ++r) {
                const int key = kt * 16 + quad * 4 + r;
                const float p0 = (key < n) ? __builtin_amdgcn_exp2f(sv0[kt][r]) : 0.f;
                const float p1 = (key < n) ? __builtin_amdgcn_exp2f(sv1[kt][r]) : 0.f;
                s0 += p0; sv0[kt][r] = p0;
                s1 += p1; sv1[kt][r] = p1;
            }
            t0[kt] = s0; t1[kt] = s1;
        }
        float ls0 = (t0[0] + t0[1]) + (t0[2] + t0[3]);
        float ls1 = (t1[0] + t1[1]) + (t1[2] + t1[3]);
        ls0 += __shfl_xor(ls0, 16, 64);
        ls1 += __shfl_xor(ls1, 16, 64);
        ls0 += __shfl_xor(ls0, 32, 64);
        ls1 += __shfl_xor(ls1, 32, 64);
        const float inv0 = __builtin_amdgcn_rcpf(ls0);
        const float inv1 = __builtin_amdgcn_rcpf(ls1);
        f16x4 pf0[4], pf1[4];
#pragma unroll
        for (int kt = 0; kt < 4; ++kt) if (kt < nt) {
#pragma unroll
            for (int r = 0; r < 4; ++r) {
                pf0[kt][r] = (_Float16)(sv0[kt][r] * inv0);
                pf1[kt][r] = (_Float16)(sv1[kt][r] * inv1);
            }
        }
        // PV with split accumulators (even/odd kt), both heads independent
        f32x4 a0A = (f32x4){0.f,0.f,0.f,0.f}, a0B = (f32x4){0.f,0.f,0.f,0.f};
        f32x4 a1A = (f32x4){0.f,0.f,0.f,0.f}, a1B = (f32x4){0.f,0.f,0.f,0.f};
#pragma unroll
        for (int kt = 0; kt < 4; ++kt) if (kt < nt) {
            if ((kt & 1) == 0) {
                a0A = __builtin_amdgcn_mfma_f32_16x16x16f16(pf0[kt], vf[0][kt], a0A, 0, 0, 0);
                a1A = __builtin_amdgcn_mfma_f32_16x16x16f16(pf1[kt], vf[1][kt], a1A, 0, 0, 0);
            } else {
                a0B = __builtin_amdgcn_mfma_f32_16x16x16f16(pf0[kt], vf[0][kt], a0B, 0, 0, 0);
                a1B = __builtin_amdgcn_mfma_f32_16x16x16f16(pf1[kt], vf[1][kt], a1B, 0, 0, 0);
            }
        }
#pragma unroll
        for (int r = 0; r < 4; ++r) {
            ctxf[0][qt][r] = (_Float16)(a0A[r] + a0B[r]);
            ctxf[1][qt][r] = (_Float16)(a1A[r] + a1B[r]);
        }
    }

    // ---- ctx -> LDS (reuse xs; all xs reads are done before this barrier) ----
    __syncthreads();
#pragma unroll
    for (int m = 0; m < 2; ++m) {
        const int h = wid * 2 + m;
#pragma unroll
        for (int qt = 0; qt < 4; ++qt) if (qt < nt) {
#pragma unroll
            for (int r = 0; r < 4; ++r)
                xs[(qt * 16 + quad * 4 + r) * LSTR + h * 16 + l15] = ctxf[m][qt][r];
        }
    }
    __syncthreads();

    // ---- out-projection, column-split: wave w -> cols [32w, 32w+32), all row tiles ----
    {
        f32x4 oacc[4][2];
#pragma unroll
        for (int t = 0; t < 4; ++t) { oacc[t][0] = (f32x4){0.f,0.f,0.f,0.f}; oacc[t][1] = (f32x4){0.f,0.f,0.f,0.f}; }
#pragma unroll
        for (int ks = 0; ks < 4; ++ks) {
            f16x8 cf[2];
#pragma unroll
            for (int c2 = 0; c2 < 2; ++c2)
                cf[c2] = *(const f16x8*)(woh + (wid * 32 + c2 * 16 + l15) * EDIM + ks * 32 + quad * 8);
#pragma unroll
            for (int t = 0; t < 4; ++t) if (t < nt) {
                const f16x8 rf = *(const f16x8*)(xs + (t * 16 + l15) * LSTR + ks * 32 + quad * 8);
                oacc[t][0] = __builtin_amdgcn_mfma_f32_16x16x32_f16(cf[0], rf, oacc[t][0], 0, 0, 0);
                oacc[t][1] = __builtin_amdgcn_mfma_f32_16x16x32_f16(cf[1], rf, oacc[t][1], 0, 0, 0);
            }
        }
        const float4 bo0 = *(const float4*)(bout + wid * 32 + quad * 4);
        const float4 bo1 = *(const float4*)(bout + wid * 32 + 16 + quad * 4);
#pragma unroll
        for (int t = 0; t < 4; ++t) if (t < nt) {
            const int row = t * 16 + l15;
            if (row < n) {
                float* orow = out + (size_t)(off + row) * EDIM + wid * 32;
                *(float4*)(orow + quad * 4) =
                    make_float4(oacc[t][0][0] + bo0.x, oacc[t][0][1] + bo0.y,
                                oacc[t][0][2] + bo0.z, oacc[t][0][3] + bo0.w);
                *(float4*)(orow + 16 + quad * 4) =
                    make_float4(oacc[t][1][0] + bo1.x, oacc[t][1][1] + bo1.y,
                                oacc[t][1][2] + bo1.z, oacc[t][1][3] + bo1.w);
            }
        }
    }
}

// ================= fallback: fused fp32 kernel (used if ws too small) =================
__global__ __launch_bounds__(256, 2) void attn_fused_kernel(
    const float* __restrict__ x, const float* __restrict__ win,
    const float* __restrict__ bin, const float* __restrict__ wout,
    const float* __restrict__ bout, const int* __restrict__ ag,
    const int* __restrict__ offs, float* __restrict__ out)
{
    __shared__ __align__(16) float xs[AMAX * XSTR];
    __shared__ __align__(16) float kvs[8][AMAX * KVSTR];
    const int b = blockIdx.x, n = ag[b], off = offs[b];
    const int tid = threadIdx.x, lane = tid & 63;
    const int wid = __builtin_amdgcn_readfirstlane(tid >> 6);
#pragma unroll
    for (int it = 0; it < 8; ++it) {
        const int f4 = it * 256 + tid;
        const int r = f4 >> 5, c = (f4 & 31) << 2;
        float4 v = make_float4(0.f, 0.f, 0.f, 0.f);
        if (r < n) v = *(const float4*)(x + (size_t)(off + r) * EDIM + c);
        float* d = xs + r * XSTR + c;
        d[0]=v.x; d[1]=v.y; d[2]=v.z; d[3]=v.w;
    }
    __syncthreads();
    float* kw = kvs[wid*2+0]; float* vw = kvs[wid*2+1];
    const float* xrow = xs + lane * XSTR;
    float ctxk[2][DHEAD];
#pragma unroll
    for (int m = 0; m < 2; ++m) {
        const int h = wid * 2 + m;
        float qa[DHEAD], ka[DHEAD], va[DHEAD];
#pragma unroll
        for (int d = 0; d < DHEAD; ++d) { qa[d]=0.f; ka[d]=0.f; va[d]=0.f; }
        const float* wq = win + (size_t)(h*DHEAD)*EDIM;
        const float* wk = win + (size_t)(EDIM + h*DHEAD)*EDIM;
        const float* wv = win + (size_t)(2*EDIM + h*DHEAD)*EDIM;
        for (int k = 0; k < EDIM; ++k) {
            const float xv = xrow[k];
#pragma unroll
            for (int d = 0; d < DHEAD; ++d) {
                qa[d] = fmaf(xv, wq[d*EDIM+k], qa[d]);
                ka[d] = fmaf(xv, wk[d*EDIM+k], ka[d]);
                va[d] = fmaf(xv, wv[d*EDIM+k], va[d]);
            }
        }
#pragma unroll
        for (int d = 0; d < DHEAD; ++d) {
            qa[d] = (qa[d] + bin[h*DHEAD+d]) * 0.25f;
            ka[d] += bin[EDIM + h*DHEAD + d];
            va[d] += bin[2*EDIM + h*DHEAD + d];
        }
#pragma unroll
        for (int d = 0; d < DHEAD; ++d) { kw[lane*KVSTR+d] = ka[d]; vw[lane*KVSTR+d] = va[d]; }
        float mrun = -1e30f, lrun = 0.f, cacc[DHEAD];
#pragma unroll
        for (int d = 0; d < DHEAD; ++d) cacc[d] = 0.f;
        const int nch = (n + 15) >> 4;
        for (int ch = 0; ch < nch; ++ch) {
            const int jb = ch << 4;
            float s[16], p[16];
#pragma unroll
            for (int jj = 0; jj < 16; ++jj) {
                const float4* kr = (const float4*)(kw + (jb + jj) * KVSTR);
                const float4 k0=kr[0],k1=kr[1],k2=kr[2],k3=kr[3];
                const float kk[16] = {k0.x,k0.y,k0.z,k0.w,k1.x,k1.y,k1.z,k1.w,
                                      k2.x,k2.y,k2.z,k2.w,k3.x,k3.y,k3.z,k3.w};
                float a = 0.f;
#pragma unroll
                for (int d = 0; d < DHEAD; ++d) a = fmaf(qa[d], kk[d], a);
                s[jj] = (jb + jj < n) ? a : -1e30f;
            }
            float mc = s[0];
#pragma unroll
            for (int jj = 1; jj < 16; ++jj) mc = fmaxf(mc, s[jj]);
            const float mnew = fmaxf(mrun, mc);
            const float alpha = __expf(mrun - mnew);
            float psum = 0.f;
#pragma unroll
            for (int jj = 0; jj < 16; ++jj) { p[jj] = __expf(s[jj]-mnew); psum += p[jj]; }
            lrun = fmaf(lrun, alpha, psum);
#pragma unroll
            for (int d = 0; d < DHEAD; ++d) cacc[d] *= alpha;
#pragma unroll
            for (int jj = 0; jj < 16; ++jj) {
                const float4* vr = (const float4*)(vw + (jb + jj) * KVSTR);
                const float4 v0=vr[0],v1=vr[1],v2=vr[2],v3=vr[3];
                const float vv[16] = {v0.x,v0.y,v0.z,v0.w,v1.x,v1.y,v1.z,v1.w,
                                      v2.x,v2.y,v2.z,v2.w,v3.x,v3.y,v3.z,v3.w};
                const float pj = p[jj];
#pragma unroll
                for (int d = 0; d < DHEAD; ++d) cacc[d] = fmaf(pj, vv[d], cacc[d]);
            }
            mrun = mnew;
        }
        const float inv = 1.0f / lrun;
#pragma unroll
        for (int d = 0; d < DHEAD; ++d) ctxk[m][d] = cacc[d] * inv;
    }
    __syncthreads();
#pragma unroll
    for (int m = 0; m < 2; ++m) {
        const int h = wid * 2 + m;
#pragma unroll
        for (int d = 0; d < DHEAD; ++d) xs[lane*XSTR + h*DHEAD + d] = ctxk[m][d];
    }
    __syncthreads();
    const int c0 = wid * 32;
#pragma unroll
    for (int ct = 0; ct < 4; ++ct) {
        const int cc = c0 + ct * 8;
        float a8[8];
#pragma unroll
        for (int j = 0; j < 8; ++j) a8[j] = 0.f;
#pragma unroll 4
        for (int e = 0; e < EDIM; ++e) {
            const float cv = xrow[e];
#pragma unroll
            for (int j = 0; j < 8; ++j) a8[j] = fmaf(cv, wout[(size_t)(cc+j)*EDIM+e], a8[j]);
        }
        if (lane < n) {
            float* orow = out + (size_t)(off + lane) * EDIM + cc;
#pragma unroll
            for (int j = 0; j < 8; ++j) orow[j] = a8[j] + bout[cc+j];
        }
    }
}

extern "C" void kernel_launch(void* const* d_in, const int* in_sizes, int n_in,
                              void* d_out, int out_size, void* d_ws, size_t ws_size,
                              hipStream_t stream) {
    const float* x   = (const float*)d_in[0];
    const float* win = (const float*)d_in[1];
    const float* bin = (const float*)d_in[2];
    const float* wo  = (const float*)d_in[3];
    const float* bo  = (const float*)d_in[4];
    const int*   ag  = (const int*)d_in[5];
    float* out = (float*)d_out;

    // ws layout: winh [49152] f16 | woh [16384] f16 | offs [NB] int
    const size_t need = (size_t)WELEM * sizeof(_Float16) + NB * sizeof(int);
    if (ws_size >= need) {
        _Float16* wh = (_Float16*)d_ws;
        int* offs = (int*)(wh + WELEM);
        prep_kernel<<<65, 256, 0, stream>>>(ag, offs, win, wo, wh);
        fused_attn_kernel<<<NB, 256, 0, stream>>>(x, wh, bin, wh + 49152, bo, ag, offs, out);
    } else {
        int* offs = (int*)d_ws;
        prep_kernel<<<1, 256, 0, stream>>>(ag, offs, nullptr, nullptr, nullptr);
        attn_fused_kernel<<<NB, 256, 0, stream>>>(x, win, bin, wo, bo, ag, offs, out);
    }
}

// Round 10
// 128.971 us; speedup vs baseline: 1.2593x; 1.0715x over previous
//
#include <hip/hip_runtime.h>

#define NB    2048
#define AMAX  64
#define EDIM  128
#define TOTAL 66560          // = 520 * 128
#define DHEAD 16
#define KVSTR 20
#define XSTR  129
#define LSTR  136            // LDS row stride in fp16 (128 + 8 pad)
#define WELEM 65536          // winh (49152) + woh (16384) halfs
#define NSLOT 8192           // 2048 blocks x 4 tile slots

typedef _Float16 f16x8 __attribute__((ext_vector_type(8)));
typedef _Float16 f16x4 __attribute__((ext_vector_type(4)));
typedef float    f32x4 __attribute__((ext_vector_type(4)));

// ---------------- prep ----------------
// block 0: exclusive scan of ag -> offs; bucket samples by nt=ceil(n/16); pack tiles
//          into uniform 4-tile blocks (nt4 | nt3+nt1 | nt2+nt2 | leftovers) and emit
//          per-slot descriptors {row0, nrem, sid, base|n<<8}. General over any ag.
// blocks 1..64: convert win (49152 f32) and wout (16384 f32) to f16 wh[].
__global__ __launch_bounds__(256) void prep_kernel(const int* __restrict__ ag,
                                                   int* __restrict__ offs,
                                                   const float* __restrict__ win,
                                                   const float* __restrict__ wout,
                                                   _Float16* __restrict__ wh,
                                                   int4* __restrict__ dsc,
                                                   int* __restrict__ nblk) {
    if (blockIdx.x == 0) {
        __shared__ int part[256];
        __shared__ int cnt[8];
        __shared__ int rk[8];
        __shared__ int cb[8];
        const int t = threadIdx.x;
        int myn[8], loc[8];
        int s = 0;
#pragma unroll
        for (int i = 0; i < 8; ++i) { myn[i] = ag[t * 8 + i]; loc[i] = s; s += myn[i]; }
        part[t] = s;
        __syncthreads();
        for (int d = 1; d < 256; d <<= 1) {
            int v = (t >= d) ? part[t - d] : 0;
            __syncthreads();
            part[t] += v;
            __syncthreads();
        }
        const int base = (t == 0) ? 0 : part[t - 1];
#pragma unroll
        for (int i = 0; i < 8; ++i) offs[t * 8 + i] = base + loc[i];

        if (dsc != nullptr) {
            // dummy descriptors everywhere first (unique sid, ns=0, base=own slot)
            for (int j = t; j < NSLOT; j += 256)
                dsc[j] = make_int4(0, 0, -(j + 1), j & 3);
            if (t < 8) { cnt[t] = 0; rk[t] = 0; }
            __syncthreads();
#pragma unroll
            for (int i = 0; i < 8; ++i)
                atomicAdd(&cnt[(myn[i] + 15) >> 4], 1);
            __syncthreads();
            if (t == 0) {
                const int c4 = cnt[4], c3 = cnt[3], c2 = cnt[2], c1 = cnt[1];
                const int p31 = (c3 < c1) ? c3 : c1;
                const int q2 = c2 >> 1, odd2 = c2 & 1;
                int u1a = c1 - p31; const int cap = odd2 ? 2 : 0;
                if (u1a > cap) u1a = cap; if (u1a < 0) u1a = 0;
                const int rem1 = c1 - p31 - u1a;
                cb[4] = 0; cb[3] = c4; cb[2] = c4 + c3;
                cb[0] = p31; cb[1] = u1a;
                nblk[0] = c4 + c3 + q2 + odd2 + ((rem1 + 3) >> 2);
            }
            __syncthreads();
#pragma unroll
            for (int i = 0; i < 8; ++i) {
                const int sid = t * 8 + i, n = myn[i], off = base + loc[i];
                const int nt = (n + 15) >> 4;
                const int r = atomicAdd(&rk[nt], 1);
                int blk, s0;
                if (nt == 4)      { blk = r;            s0 = 0; }
                else if (nt == 3) { blk = cb[3] + r;    s0 = 0; }
                else if (nt == 2) { blk = cb[2] + (r >> 1); s0 = (r & 1) << 1; }
                else {
                    const int p31 = cb[0], u1a = cb[1], c2 = cnt[2];
                    if (r < p31)            { blk = cb[3] + r;          s0 = 3; }
                    else if (r < p31 + u1a) { blk = cb[2] + (c2 >> 1);  s0 = 2 + (r - p31); }
                    else {
                        const int rr = r - p31 - u1a;
                        blk = cb[2] + (c2 >> 1) + (c2 & 1) + (rr >> 2);
                        s0 = rr & 3;
                    }
                }
                for (int tt = 0; tt < nt; ++tt) {
                    int nrem = n - tt * 16; if (nrem > 16) nrem = 16;
                    dsc[blk * 4 + s0 + tt] = make_int4(off + tt * 16, nrem, sid, s0 | (n << 8));
                }
            }
        }
    } else {
        // blocks 1..48 -> win, 49..64 -> wout (1024-elem chunks never straddle)
        const int base = (blockIdx.x - 1) * 1024 + threadIdx.x * 4;
        const float4 v = (base < 49152) ? *(const float4*)(win + base)
                                        : *(const float4*)(wout + (base - 49152));
        f16x4 h;
        h[0] = (_Float16)v.x; h[1] = (_Float16)v.y;
        h[2] = (_Float16)v.z; h[3] = (_Float16)v.w;
        *(f16x4*)(wh + base) = h;
    }
}

// ---------------- fully fused, tile-packed ----------------
// Uniform 4-tile blocks (descriptors from prep). 4 waves; wave w owns heads {2w,2w+1}
// interleaved. Per slot t: {row0, nrem, sid, base|ns<<8}. Attention is block-diagonal
// over slots: q-slot qt attends k-slots with equal sid; key index (kt-base)*16+... < ns.
// All MFMA fragment layouts identical to the r9-proven body. Garbage rows of padded/
// dummy slots are confined by MFMA row-independence and never stored.
__global__ __launch_bounds__(256, 2) void fused_attn_kernel(
    const float*    __restrict__ x,     // [TOTAL][128] f32
    const _Float16* __restrict__ winh,  // [384][128] f16
    const float*    __restrict__ bin,   // [384] f32
    const _Float16* __restrict__ woh,   // [128][128] f16
    const float*    __restrict__ bout,  // [128] f32
    const int4*     __restrict__ dsc,
    const int*      __restrict__ nblk,
    float*          __restrict__ out)   // [TOTAL][128] f32
{
    __shared__ __align__(16) _Float16 xs[AMAX * LSTR];   // 17408 B; x tile, then ctx

    const int b = blockIdx.x;
    if (b >= nblk[0]) return;
    const int tid  = threadIdx.x;
    const int lane = tid & 63;
    const int wid  = __builtin_amdgcn_readfirstlane(tid >> 6);
    const int l15  = lane & 15;
    const int quad = lane >> 4;

    int4 dd[4];
#pragma unroll
    for (int t = 0; t < 4; ++t) dd[t] = dsc[b * 4 + t];

    // ---- weight fragments + biases FIRST: latency overlaps the x stage below ----
    f16x8 wq[2][4], wk[2][4], wv[2][4];
    float bqa[2][4], bka[2][4], bva[2];
#pragma unroll
    for (int m = 0; m < 2; ++m) {
        const int h = wid * 2 + m;
#pragma unroll
        for (int ks = 0; ks < 4; ++ks) {
            wq[m][ks] = *(const f16x8*)(winh + (size_t)(h * 16 + l15) * EDIM + ks * 32 + quad * 8);
            wk[m][ks] = *(const f16x8*)(winh + (size_t)(128 + h * 16 + l15) * EDIM + ks * 32 + quad * 8);
            wv[m][ks] = *(const f16x8*)(winh + (size_t)(256 + h * 16 + l15) * EDIM + ks * 32 + quad * 8);
        }
        const float4 bq = *(const float4*)(bin + h * 16 + quad * 4);
        const float4 bk = *(const float4*)(bin + 128 + h * 16 + quad * 4);
        bqa[m][0]=bq.x; bqa[m][1]=bq.y; bqa[m][2]=bq.z; bqa[m][3]=bq.w;
        bka[m][0]=bk.x; bka[m][1]=bk.y; bka[m][2]=bk.z; bka[m][3]=bk.w;
        bva[m] = bin[256 + h * 16 + l15];
    }

    // ---- stage x -> xs (f16) per slot; rows >= nrem zero-filled ----
    {
        const int rr = tid >> 4, c8 = tid & 15;   // 16 rows x 16 chunks = 256 threads
#pragma unroll
        for (int t = 0; t < 4; ++t) {
            f16x8 hv = {};
            if (rr < dd[t].y) {
                const float* xr = x + (size_t)(dd[t].x + rr) * EDIM + c8 * 8;
                const float4 a0 = *(const float4*)xr;
                const float4 a1 = *(const float4*)(xr + 4);
                hv[0]=(_Float16)a0.x; hv[1]=(_Float16)a0.y; hv[2]=(_Float16)a0.z; hv[3]=(_Float16)a0.w;
                hv[4]=(_Float16)a1.x; hv[5]=(_Float16)a1.y; hv[6]=(_Float16)a1.z; hv[7]=(_Float16)a1.w;
            }
            *(f16x8*)(xs + (t * 16 + rr) * LSTR + c8 * 8) = hv;
        }
    }
    __syncthreads();

    // ---- QKV projection: uniform over all 4 slots ----
    const float QSC = 0.25f * 1.44269504088896f;    // fold 1/sqrt(16) * log2(e)
    f16x4 qf[2][4], kf[2][4], vf[2][4];
#pragma unroll
    for (int kt = 0; kt < 4; ++kt) {
        f16x8 xf[4];
#pragma unroll
        for (int ks = 0; ks < 4; ++ks)
            xf[ks] = *(const f16x8*)(xs + (kt * 16 + l15) * LSTR + ks * 32 + quad * 8);
#pragma unroll
        for (int m = 0; m < 2; ++m) {
            f32x4 aq = (f32x4){0.f,0.f,0.f,0.f};
            f32x4 ak = (f32x4){0.f,0.f,0.f,0.f};
            f32x4 av = (f32x4){0.f,0.f,0.f,0.f};
#pragma unroll
            for (int ks = 0; ks < 4; ++ks) {
                aq = __builtin_amdgcn_mfma_f32_16x16x32_f16(wq[m][ks], xf[ks], aq, 0, 0, 0);
                ak = __builtin_amdgcn_mfma_f32_16x16x32_f16(wk[m][ks], xf[ks], ak, 0, 0, 0);
                av = __builtin_amdgcn_mfma_f32_16x16x32_f16(xf[ks], wv[m][ks], av, 0, 0, 0);
            }
#pragma unroll
            for (int r = 0; r < 4; ++r) {
                qf[m][kt][r] = (_Float16)((aq[r] + bqa[m][r]) * QSC);
                kf[m][kt][r] = (_Float16)(ak[r] + bka[m][r]);
                vf[m][kt][r] = (_Float16)(av[r] + bva[m]);
            }
        }
    }

    // ---- attention: block-diagonal over slots; both heads interleaved ----
    f16x4 ctxf[2][4] = {};   // [head m][q-slot]; elem r -> qrow=quad*4+r (local), d=l15
#pragma unroll
    for (int qt = 0; qt < 4; ++qt) {
        const int baseq = dd[qt].w & 255;
        const int nsq   = dd[qt].w >> 8;
        const int sidq  = dd[qt].z;
        bool act[4];
#pragma unroll
        for (int kt = 0; kt < 4; ++kt) act[kt] = (dd[kt].z == sidq);

        f32x4 sv0[4], sv1[4];
#pragma unroll
        for (int kt = 0; kt < 4; ++kt) if (act[kt]) {
            sv0[kt] = __builtin_amdgcn_mfma_f32_16x16x16f16(
                          kf[0][kt], qf[0][qt], (f32x4){0.f,0.f,0.f,0.f}, 0, 0, 0);
            sv1[kt] = __builtin_amdgcn_mfma_f32_16x16x16f16(
                          kf[1][kt], qf[1][qt], (f32x4){0.f,0.f,0.f,0.f}, 0, 0, 0);
        }
        float t0[4], t1[4];
#pragma unroll
        for (int kt = 0; kt < 4; ++kt) { t0[kt] = 0.f; t1[kt] = 0.f; }
#pragma unroll
        for (int kt = 0; kt < 4; ++kt) if (act[kt]) {
            float s0 = 0.f, s1 = 0.f;
#pragma unroll
            for (int r = 0; r < 4; ++r) {
                const int key = (kt - baseq) * 16 + quad * 4 + r;
                const float p0 = (key < nsq) ? __builtin_amdgcn_exp2f(sv0[kt][r]) : 0.f;
                const float p1 = (key < nsq) ? __builtin_amdgcn_exp2f(sv1[kt][r]) : 0.f;
                s0 += p0; sv0[kt][r] = p0;
                s1 += p1; sv1[kt][r] = p1;
            }
            t0[kt] = s0; t1[kt] = s1;
        }
        float ls0 = (t0[0] + t0[1]) + (t0[2] + t0[3]);
        float ls1 = (t1[0] + t1[1]) + (t1[2] + t1[3]);
        ls0 += __shfl_xor(ls0, 16, 64);
        ls1 += __shfl_xor(ls1, 16, 64);
        ls0 += __shfl_xor(ls0, 32, 64);
        ls1 += __shfl_xor(ls1, 32, 64);
        const float inv0 = __builtin_amdgcn_rcpf(ls0);
        const float inv1 = __builtin_amdgcn_rcpf(ls1);
        f16x4 pf0[4], pf1[4];
#pragma unroll
        for (int kt = 0; kt < 4; ++kt) if (act[kt]) {
#pragma unroll
            for (int r = 0; r < 4; ++r) {
                pf0[kt][r] = (_Float16)(sv0[kt][r] * inv0);
                pf1[kt][r] = (_Float16)(sv1[kt][r] * inv1);
            }
        }
        f32x4 a0A = (f32x4){0.f,0.f,0.f,0.f}, a0B = (f32x4){0.f,0.f,0.f,0.f};
        f32x4 a1A = (f32x4){0.f,0.f,0.f,0.f}, a1B = (f32x4){0.f,0.f,0.f,0.f};
#pragma unroll
        for (int kt = 0; kt < 4; ++kt) if (act[kt]) {
            if ((kt & 1) == 0) {
                a0A = __builtin_amdgcn_mfma_f32_16x16x16f16(pf0[kt], vf[0][kt], a0A, 0, 0, 0);
                a1A = __builtin_amdgcn_mfma_f32_16x16x16f16(pf1[kt], vf[1][kt], a1A, 0, 0, 0);
            } else {
                a0B = __builtin_amdgcn_mfma_f32_16x16x16f16(pf0[kt], vf[0][kt], a0B, 0, 0, 0);
                a1B = __builtin_amdgcn_mfma_f32_16x16x16f16(pf1[kt], vf[1][kt], a1B, 0, 0, 0);
            }
        }
#pragma unroll
        for (int r = 0; r < 4; ++r) {
            ctxf[0][qt][r] = (_Float16)(a0A[r] + a0B[r]);
            ctxf[1][qt][r] = (_Float16)(a1A[r] + a1B[r]);
        }
    }

    // ---- ctx -> LDS (reuse xs; all xs reads done before this barrier) ----
    __syncthreads();
#pragma unroll
    for (int m = 0; m < 2; ++m) {
        const int h = wid * 2 + m;
#pragma unroll
        for (int qt = 0; qt < 4; ++qt) {
#pragma unroll
            for (int r = 0; r < 4; ++r)
                xs[(qt * 16 + quad * 4 + r) * LSTR + h * 16 + l15] = ctxf[m][qt][r];
        }
    }
    __syncthreads();

    // ---- out-projection, column-split: wave w -> cols [32w,32w+32), all 4 slots ----
    {
        f32x4 oacc[4][2];
#pragma unroll
        for (int t = 0; t < 4; ++t) { oacc[t][0] = (f32x4){0.f,0.f,0.f,0.f}; oacc[t][1] = (f32x4){0.f,0.f,0.f,0.f}; }
#pragma unroll
        for (int ks = 0; ks < 4; ++ks) {
            f16x8 cf[2];
#pragma unroll
            for (int c2 = 0; c2 < 2; ++c2)
                cf[c2] = *(const f16x8*)(woh + (wid * 32 + c2 * 16 + l15) * EDIM + ks * 32 + quad * 8);
#pragma unroll
            for (int t = 0; t < 4; ++t) {
                const f16x8 rf = *(const f16x8*)(xs + (t * 16 + l15) * LSTR + ks * 32 + quad * 8);
                oacc[t][0] = __builtin_amdgcn_mfma_f32_16x16x32_f16(cf[0], rf, oacc[t][0], 0, 0, 0);
                oacc[t][1] = __builtin_amdgcn_mfma_f32_16x16x32_f16(cf[1], rf, oacc[t][1], 0, 0, 0);
            }
        }
        const float4 bo0 = *(const float4*)(bout + wid * 32 + quad * 4);
        const float4 bo1 = *(const float4*)(bout + wid * 32 + 16 + quad * 4);
#pragma unroll
        for (int t = 0; t < 4; ++t) {
            if (l15 < dd[t].y) {
                float* orow = out + (size_t)(dd[t].x + l15) * EDIM + wid * 32;
                *(float4*)(orow + quad * 4) =
                    make_float4(oacc[t][0][0] + bo0.x, oacc[t][0][1] + bo0.y,
                                oacc[t][0][2] + bo0.z, oacc[t][0][3] + bo0.w);
                *(float4*)(orow + 16 + quad * 4) =
                    make_float4(oacc[t][1][0] + bo1.x, oacc[t][1][1] + bo1.y,
                                oacc[t][1][2] + bo1.z, oacc[t][1][3] + bo1.w);
            }
        }
    }
}

// ================= fallback: fused fp32 kernel (used if ws too small) =================
__global__ __launch_bounds__(256, 2) void attn_fused_kernel(
    const float* __restrict__ x, const float* __restrict__ win,
    const float* __restrict__ bin, const float* __restrict__ wout,
    const float* __restrict__ bout, const int* __restrict__ ag,
    const int* __restrict__ offs, float* __restrict__ out)
{
    __shared__ __align__(16) float xs[AMAX * XSTR];
    __shared__ __align__(16) float kvs[8][AMAX * KVSTR];
    const int b = blockIdx.x, n = ag[b], off = offs[b];
    const int tid = threadIdx.x, lane = tid & 63;
    const int wid = __builtin_amdgcn_readfirstlane(tid >> 6);
#pragma unroll
    for (int it = 0; it < 8; ++it) {
        const int f4 = it * 256 + tid;
        const int r = f4 >> 5, c = (f4 & 31) << 2;
        float4 v = make_float4(0.f, 0.f, 0.f, 0.f);
        if (r < n) v = *(const float4*)(x + (size_t)(off + r) * EDIM + c);
        float* d = xs + r * XSTR + c;
        d[0]=v.x; d[1]=v.y; d[2]=v.z; d[3]=v.w;
    }
    __syncthreads();
    float* kw = kvs[wid*2+0]; float* vw = kvs[wid*2+1];
    const float* xrow = xs + lane * XSTR;
    float ctxk[2][DHEAD];
#pragma unroll
    for (int m = 0; m < 2; ++m) {
        const int h = wid * 2 + m;
        float qa[DHEAD], ka[DHEAD], va[DHEAD];
#pragma unroll
        for (int d = 0; d < DHEAD; ++d) { qa[d]=0.f; ka[d]=0.f; va[d]=0.f; }
        const float* wq = win + (size_t)(h*DHEAD)*EDIM;
        const float* wk = win + (size_t)(EDIM + h*DHEAD)*EDIM;
        const float* wv = win + (size_t)(2*EDIM + h*DHEAD)*EDIM;
        for (int k = 0; k < EDIM; ++k) {
            const float xv = xrow[k];
#pragma unroll
            for (int d = 0; d < DHEAD; ++d) {
                qa[d] = fmaf(xv, wq[d*EDIM+k], qa[d]);
                ka[d] = fmaf(xv, wk[d*EDIM+k], ka[d]);
                va[d] = fmaf(xv, wv[d*EDIM+k], va[d]);
            }
        }
#pragma unroll
        for (int d = 0; d < DHEAD; ++d) {
            qa[d] = (qa[d] + bin[h*DHEAD+d]) * 0.25f;
            ka[d] += bin[EDIM + h*DHEAD + d];
            va[d] += bin[2*EDIM + h*DHEAD + d];
        }
#pragma unroll
        for (int d = 0; d < DHEAD; ++d) { kw[lane*KVSTR+d] = ka[d]; vw[lane*KVSTR+d] = va[d]; }
        float mrun = -1e30f, lrun = 0.f, cacc[DHEAD];
#pragma unroll
        for (int d = 0; d < DHEAD; ++d) cacc[d] = 0.f;
        const int nch = (n + 15) >> 4;
        for (int ch = 0; ch < nch; ++ch) {
            const int jb = ch << 4;
            float s[16], p[16];
#pragma unroll
            for (int jj = 0; jj < 16; ++jj) {
                const float4* kr = (const float4*)(kw + (jb + jj) * KVSTR);
                const float4 k0=kr[0],k1=kr[1],k2=kr[2],k3=kr[3];
                const float kk[16] = {k0.x,k0.y,k0.z,k0.w,k1.x,k1.y,k1.z,k1.w,
                                      k2.x,k2.y,k2.z,k2.w,k3.x,k3.y,k3.z,k3.w};
                float a = 0.f;
#pragma unroll
                for (int d = 0; d < DHEAD; ++d) a = fmaf(qa[d], kk[d], a);
                s[jj] = (jb + jj < n) ? a : -1e30f;
            }
            float mc = s[0];
#pragma unroll
            for (int jj = 1; jj < 16; ++jj) mc = fmaxf(mc, s[jj]);
            const float mnew = fmaxf(mrun, mc);
            const float alpha = __expf(mrun - mnew);
            float psum = 0.f;
#pragma unroll
            for (int jj = 0; jj < 16; ++jj) { p[jj] = __expf(s[jj]-mnew); psum += p[jj]; }
            lrun = fmaf(lrun, alpha, psum);
#pragma unroll
            for (int d = 0; d < DHEAD; ++d) cacc[d] *= alpha;
#pragma unroll
            for (int jj = 0; jj < 16; ++jj) {
                const float4* vr = (const float4*)(vw + (jb + jj) * KVSTR);
                const float4 v0=vr[0],v1=vr[1],v2=vr[2],v3=vr[3];
                const float vv[16] = {v0.x,v0.y,v0.z,v0.w,v1.x,v1.y,v1.z,v1.w,
                                      v2.x,v2.y,v2.z,v2.w,v3.x,v3.y,v3.z,v3.w};
                const float pj = p[jj];
#pragma unroll
                for (int d = 0; d < DHEAD; ++d) cacc[d] = fmaf(pj, vv[d], cacc[d]);
            }
            mrun = mnew;
        }
        const float inv = 1.0f / lrun;
#pragma unroll
        for (int d = 0; d < DHEAD; ++d) ctxk[m][d] = cacc[d] * inv;
    }
    __syncthreads();
#pragma unroll
    for (int m = 0; m < 2; ++m) {
        const int h = wid * 2 + m;
#pragma unroll
        for (int d = 0; d < DHEAD; ++d) xs[lane*XSTR + h*DHEAD + d] = ctxk[m][d];
    }
    __syncthreads();
    const int c0 = wid * 32;
#pragma unroll
    for (int ct = 0; ct < 4; ++ct) {
        const int cc = c0 + ct * 8;
        float a8[8];
#pragma unroll
        for (int j = 0; j < 8; ++j) a8[j] = 0.f;
#pragma unroll 4
        for (int e = 0; e < EDIM; ++e) {
            const float cv = xrow[e];
#pragma unroll
            for (int j = 0; j < 8; ++j) a8[j] = fmaf(cv, wout[(size_t)(cc+j)*EDIM+e], a8[j]);
        }
        if (lane < n) {
            float* orow = out + (size_t)(off + lane) * EDIM + cc;
#pragma unroll
            for (int j = 0; j < 8; ++j) orow[j] = a8[j] + bout[cc+j];
        }
    }
}

extern "C" void kernel_launch(void* const* d_in, const int* in_sizes, int n_in,
                              void* d_out, int out_size, void* d_ws, size_t ws_size,
                              hipStream_t stream) {
    const float* x   = (const float*)d_in[0];
    const float* win = (const float*)d_in[1];
    const float* bin = (const float*)d_in[2];
    const float* wo  = (const float*)d_in[3];
    const float* bo  = (const float*)d_in[4];
    const int*   ag  = (const int*)d_in[5];
    float* out = (float*)d_out;

    // ws layout: wh [WELEM] f16 | dsc [NSLOT] int4 | offs [NB] int | nblk [4] int
    const size_t need = (size_t)WELEM * sizeof(_Float16) + (size_t)NSLOT * sizeof(int4)
                      + NB * sizeof(int) + 4 * sizeof(int);
    if (ws_size >= need) {
        _Float16* wh = (_Float16*)d_ws;
        int4* dsc = (int4*)(wh + WELEM);
        int* offs = (int*)(dsc + NSLOT);
        int* nblk = offs + NB;
        prep_kernel<<<65, 256, 0, stream>>>(ag, offs, win, wo, wh, dsc, nblk);
        fused_attn_kernel<<<NB, 256, 0, stream>>>(x, wh, bin, wh + 49152, bo, dsc, nblk, out);
    } else {
        int* offs = (int*)d_ws;
        prep_kernel<<<1, 256, 0, stream>>>(ag, offs, nullptr, nullptr, nullptr, nullptr, nullptr);
        attn_fused_kernel<<<NB, 256, 0, stream>>>(x, win, bin, wo, bo, ag, offs, out);
    }
}